// Round 1
// baseline (70.984 us; speedup 1.0000x reference)
//
#include <hip/hip_runtime.h>

#define BB 8
#define NN 4096
#define THREADS 256

// bid = dir*128 + b*16 + jb ; dir0: db=a1,q=a2 (dist1), dir1: db=a2,q=a1 (dist2)
__global__ __launch_bounds__(THREADS) void chamfer_min_kernel(
    const float* __restrict__ a1, const float* __restrict__ a2,
    float* __restrict__ partials)
{
    __shared__ float sdb[NN * 3];
    __shared__ float red[THREADS];

    const int tid = threadIdx.x;
    const int bid = blockIdx.x;
    const int jb  = bid & 15;
    const int b   = (bid >> 4) & 7;
    const int dir = bid >> 7;

    const float* dbg = (dir == 0 ? a1 : a2) + (size_t)b * NN * 3;
    const float* qg  = (dir == 0 ? a2 : a1) + (size_t)b * NN * 3;

    // stage database cloud (48 KB) into LDS, coalesced float4
    const float4* src4 = reinterpret_cast<const float4*>(dbg);
    float4* dst4 = reinterpret_cast<float4*>(sdb);
    #pragma unroll
    for (int k = 0; k < (NN * 3 / 4) / THREADS; ++k)
        dst4[tid + k * THREADS] = src4[tid + k * THREADS];

    // own query point
    const int j = jb * THREADS + tid;
    const float qx = qg[j * 3 + 0];
    const float qy = qg[j * 3 + 1];
    const float qz = qg[j * 3 + 2];

    __syncthreads();

    float m0 = 3.4e38f, m1 = 3.4e38f, m2 = 3.4e38f, m3 = 3.4e38f;
    float m4 = 3.4e38f, m5 = 3.4e38f, m6 = 3.4e38f, m7 = 3.4e38f;

    #pragma unroll 2
    for (int i = 0; i < NN; i += 8) {
        const float* p = &sdb[i * 3];
        float dx, dy, dz, d;
        dx = p[ 0] - qx; dy = p[ 1] - qy; dz = p[ 2] - qz; d = dx*dx + dy*dy + dz*dz; m0 = fminf(m0, d);
        dx = p[ 3] - qx; dy = p[ 4] - qy; dz = p[ 5] - qz; d = dx*dx + dy*dy + dz*dz; m1 = fminf(m1, d);
        dx = p[ 6] - qx; dy = p[ 7] - qy; dz = p[ 8] - qz; d = dx*dx + dy*dy + dz*dz; m2 = fminf(m2, d);
        dx = p[ 9] - qx; dy = p[10] - qy; dz = p[11] - qz; d = dx*dx + dy*dy + dz*dz; m3 = fminf(m3, d);
        dx = p[12] - qx; dy = p[13] - qy; dz = p[14] - qz; d = dx*dx + dy*dy + dz*dz; m4 = fminf(m4, d);
        dx = p[15] - qx; dy = p[16] - qy; dz = p[17] - qz; d = dx*dx + dy*dy + dz*dz; m5 = fminf(m5, d);
        dx = p[18] - qx; dy = p[19] - qy; dz = p[20] - qz; d = dx*dx + dy*dy + dz*dz; m6 = fminf(m6, d);
        dx = p[21] - qx; dy = p[22] - qy; dz = p[23] - qz; d = dx*dx + dy*dy + dz*dz; m7 = fminf(m7, d);
    }

    float m = fminf(fminf(fminf(m0, m1), fminf(m2, m3)),
                    fminf(fminf(m4, m5), fminf(m6, m7)));

    // block reduction: sum of per-query mins
    red[tid] = m;
    __syncthreads();
    #pragma unroll
    for (int s = THREADS / 2; s > 0; s >>= 1) {
        if (tid < s) red[tid] += red[tid + s];
        __syncthreads();
    }
    if (tid == 0) partials[bid] = red[0];
}

__global__ __launch_bounds__(256) void finalize_kernel(
    const float* __restrict__ partials, float* __restrict__ out)
{
    __shared__ float red[256];
    const int t = threadIdx.x;
    red[t] = partials[t];
    __syncthreads();
    #pragma unroll
    for (int s = 64; s > 0; s >>= 1) {
        if ((t & 127) < s) red[t] += red[t + s];
        __syncthreads();
    }
    if (t == 0) {
        const float inv = 1.0f / (float)(BB * NN);
        const float d1 = red[0]   * inv;   // dir0: min over a1 for each a2 point
        const float d2 = red[128] * inv;   // dir1: min over a2 for each a1 point
        out[0] = d1 + d2;
        out[1] = d1;
        out[2] = d2;
    }
}

extern "C" void kernel_launch(void* const* d_in, const int* in_sizes, int n_in,
                              void* d_out, int out_size, void* d_ws, size_t ws_size,
                              hipStream_t stream)
{
    const float* a1 = (const float*)d_in[0];
    const float* a2 = (const float*)d_in[1];
    float* out      = (float*)d_out;
    float* partials = (float*)d_ws;   // 256 floats used

    hipLaunchKernelGGL(chamfer_min_kernel, dim3(256), dim3(THREADS), 0, stream,
                       a1, a2, partials);
    hipLaunchKernelGGL(finalize_kernel, dim3(1), dim3(256), 0, stream,
                       partials, out);
}

// Round 2
// 41.203 us; speedup vs baseline: 1.7228x; 1.7228x over previous
//
#include <hip/hip_runtime.h>

#define BB 8
#define NN 4096
#define THREADS 256
#define NSPLIT 8
#define CHUNK (NN / NSPLIT)   // 512 DB points per block
#define QPB 512               // queries per block (2 per thread)
#define NQ_TOTAL (2 * BB * NN)  // 65536

__device__ __forceinline__ unsigned enc_f(float f) {
    unsigned u = __float_as_uint(f);
    return u ^ (unsigned)(((int)u >> 31) | 0x80000000);
}
__device__ __forceinline__ float dec_f(unsigned u) {
    unsigned v = (u & 0x80000000u) ? (u ^ 0x80000000u) : ~u;
    return __uint_as_float(v);
}

// bid = dir*512 + b*64 + qb*8 + c
__global__ __launch_bounds__(THREADS) void chamfer_min_kernel(
    const float* __restrict__ a1, const float* __restrict__ a2,
    unsigned int* __restrict__ minenc)
{
    __shared__ float4 sdb[CHUNK];

    const int tid = threadIdx.x;
    const int bid = blockIdx.x;
    const int c   = bid & 7;
    const int qb  = (bid >> 3) & 7;
    const int b   = (bid >> 6) & 7;
    const int dir = bid >> 9;

    const float* dbg = (dir == 0 ? a1 : a2) + (size_t)b * NN * 3;
    const float* qg  = (dir == 0 ? a2 : a1) + (size_t)b * NN * 3;

    // stage CHUNK db points as float4(x,y,z,||p||^2)
    {
        const int i0 = c * CHUNK + tid;
        float x = dbg[i0 * 3 + 0], y = dbg[i0 * 3 + 1], z = dbg[i0 * 3 + 2];
        sdb[tid] = make_float4(x, y, z, fmaf(x, x, fmaf(y, y, z * z)));
        const int i1 = i0 + 256;
        x = dbg[i1 * 3 + 0]; y = dbg[i1 * 3 + 1]; z = dbg[i1 * 3 + 2];
        sdb[tid + 256] = make_float4(x, y, z, fmaf(x, x, fmaf(y, y, z * z)));
    }

    // two query points per thread
    const int qA = qb * QPB + tid;
    const int qB = qA + 256;
    const float ax = qg[qA * 3 + 0], ay = qg[qA * 3 + 1], az = qg[qA * 3 + 2];
    const float bx = qg[qB * 3 + 0], by = qg[qB * 3 + 1], bz = qg[qB * 3 + 2];

    __syncthreads();

    float mA0 = 3.4e38f, mA1 = 3.4e38f, mB0 = 3.4e38f, mB1 = 3.4e38f;

    #pragma unroll 2
    for (int i = 0; i < CHUNK; i += 2) {
        const float4 p0 = sdb[i];
        const float4 p1 = sdb[i + 1];
        // t = ||p||^2 - 2 p.q   (add ||q||^2 later, after the global min)
        float dA0 = fmaf(p0.z, az, fmaf(p0.y, ay, p0.x * ax));
        float dB0 = fmaf(p0.z, bz, fmaf(p0.y, by, p0.x * bx));
        float dA1 = fmaf(p1.z, az, fmaf(p1.y, ay, p1.x * ax));
        float dB1 = fmaf(p1.z, bz, fmaf(p1.y, by, p1.x * bx));
        mA0 = fminf(mA0, fmaf(dA0, -2.0f, p0.w));
        mB0 = fminf(mB0, fmaf(dB0, -2.0f, p0.w));
        mA1 = fminf(mA1, fmaf(dA1, -2.0f, p1.w));
        mB1 = fminf(mB1, fmaf(dB1, -2.0f, p1.w));
    }

    const float mA = fminf(mA0, mA1);
    const float mB = fminf(mB0, mB1);

    const int base = dir * (BB * NN) + b * NN;
    atomicMin(&minenc[base + qA], enc_f(mA));
    atomicMin(&minenc[base + qB], enc_f(mB));
}

// 256 blocks x 256 threads: decode min-t, add ||q||^2, block-sum
__global__ __launch_bounds__(THREADS) void decode_sum_kernel(
    const float* __restrict__ a1, const float* __restrict__ a2,
    const unsigned int* __restrict__ minenc, float* __restrict__ partials)
{
    __shared__ float red[THREADS];
    const int tid = threadIdx.x;
    const int bid = blockIdx.x;
    const int gq  = bid * THREADS + tid;
    const int dir = gq >> 15;
    const int b   = (gq >> 12) & 7;
    const int q   = gq & (NN - 1);

    const float* qg = (dir == 0 ? a2 : a1) + ((size_t)b * NN + q) * 3;
    const float qx = qg[0], qy = qg[1], qz = qg[2];
    const float qn = fmaf(qx, qx, fmaf(qy, qy, qz * qz));
    const float d  = dec_f(minenc[gq]) + qn;

    red[tid] = d;
    __syncthreads();
    #pragma unroll
    for (int s = THREADS / 2; s > 0; s >>= 1) {
        if (tid < s) red[tid] += red[tid + s];
        __syncthreads();
    }
    if (tid == 0) partials[bid] = red[0];
}

__global__ __launch_bounds__(256) void finalize_kernel(
    const float* __restrict__ partials, float* __restrict__ out)
{
    __shared__ float red[256];
    const int t = threadIdx.x;
    red[t] = partials[t];
    __syncthreads();
    #pragma unroll
    for (int s = 64; s > 0; s >>= 1) {
        if ((t & 127) < s) red[t] += red[t + s];
        __syncthreads();
    }
    if (t == 0) {
        const float inv = 1.0f / (float)(BB * NN);
        const float d1 = red[0]   * inv;   // dir0
        const float d2 = red[128] * inv;   // dir1
        out[0] = d1 + d2;
        out[1] = d1;
        out[2] = d2;
    }
}

extern "C" void kernel_launch(void* const* d_in, const int* in_sizes, int n_in,
                              void* d_out, int out_size, void* d_ws, size_t ws_size,
                              hipStream_t stream)
{
    const float* a1 = (const float*)d_in[0];
    const float* a2 = (const float*)d_in[1];
    float* out = (float*)d_out;

    unsigned int* minenc = (unsigned int*)d_ws;                      // 65536 u32 = 256 KB
    float* partials = (float*)((char*)d_ws + NQ_TOTAL * sizeof(unsigned)); // 256 floats

    hipMemsetAsync(minenc, 0xFF, NQ_TOTAL * sizeof(unsigned), stream);

    hipLaunchKernelGGL(chamfer_min_kernel, dim3(2 * BB * 8 * NSPLIT), dim3(THREADS), 0, stream,
                       a1, a2, minenc);
    hipLaunchKernelGGL(decode_sum_kernel, dim3(NQ_TOTAL / THREADS), dim3(THREADS), 0, stream,
                       a1, a2, minenc, partials);
    hipLaunchKernelGGL(finalize_kernel, dim3(1), dim3(256), 0, stream,
                       partials, out);
}

// Round 3
// 32.948 us; speedup vs baseline: 2.1545x; 1.2506x over previous
//
#include <hip/hip_runtime.h>

#define BB 8
#define NN 4096
#define THREADS 256
#define NSPLIT 16
#define CHUNK (NN / NSPLIT)     // 256 DB points per block
#define QPT 8                   // queries per thread
#define QPB (THREADS * QPT)     // 2048 queries per block
#define NQ_TOTAL (2 * BB * NN)  // 65536

// bid = dir*256 + b*32 + qb*16 + c ; dir0: db=a1,q=a2 (dist1), dir1: db=a2,q=a1
__global__ __launch_bounds__(THREADS) void chamfer_min_kernel(
    const float* __restrict__ a1, const float* __restrict__ a2,
    float* __restrict__ minpart)
{
    __shared__ float4 sdb[CHUNK];

    const int tid = threadIdx.x;
    const int bid = blockIdx.x;
    const int c   = bid & 15;
    const int qb  = (bid >> 4) & 1;
    const int b   = (bid >> 5) & 7;
    const int dir = bid >> 8;

    const float* dbg = (dir == 0 ? a1 : a2) + (size_t)b * NN * 3;
    const float* qg  = (dir == 0 ? a2 : a1) + (size_t)b * NN * 3;

    // stage CHUNK db points as (x, y, z, ||p||^2 / 2)
    {
        const int i = c * CHUNK + tid;   // CHUNK == THREADS
        const float x = dbg[i * 3 + 0];
        const float y = dbg[i * 3 + 1];
        const float z = dbg[i * 3 + 2];
        sdb[tid] = make_float4(x, y, z, 0.5f * fmaf(x, x, fmaf(y, y, z * z)));
    }

    // 8 consecutive queries per thread (24 floats = 6 aligned float4 loads), negated
    float qx[QPT], qy[QPT], qz[QPT];
    {
        const float4* q4 = reinterpret_cast<const float4*>(
            qg + (size_t)(qb * QPB + tid * QPT) * 3);
        const float4 v0 = q4[0], v1 = q4[1], v2 = q4[2];
        const float4 v3 = q4[3], v4 = q4[4], v5 = q4[5];
        qx[0] = -v0.x; qy[0] = -v0.y; qz[0] = -v0.z;
        qx[1] = -v0.w; qy[1] = -v1.x; qz[1] = -v1.y;
        qx[2] = -v1.z; qy[2] = -v1.w; qz[2] = -v2.x;
        qx[3] = -v2.y; qy[3] = -v2.z; qz[3] = -v2.w;
        qx[4] = -v3.x; qy[4] = -v3.y; qz[4] = -v3.z;
        qx[5] = -v3.w; qy[5] = -v4.x; qz[5] = -v4.y;
        qx[6] = -v4.z; qy[6] = -v4.w; qz[6] = -v5.x;
        qx[7] = -v5.y; qy[7] = -v5.z; qz[7] = -v5.w;
    }

    __syncthreads();

    float m0[QPT], m1[QPT];
    #pragma unroll
    for (int k = 0; k < QPT; ++k) { m0[k] = 3.4e38f; m1[k] = 3.4e38f; }

    // t' = ||p||^2/2 - p.q  (4 VALU per pair: 3 fma + 1 min)
    #pragma unroll 2
    for (int i = 0; i < CHUNK; i += 2) {
        const float4 p0 = sdb[i];
        const float4 p1 = sdb[i + 1];
        #pragma unroll
        for (int k = 0; k < QPT; ++k) {
            const float t0 = fmaf(p0.x, qx[k], fmaf(p0.y, qy[k], fmaf(p0.z, qz[k], p0.w)));
            const float t1 = fmaf(p1.x, qx[k], fmaf(p1.y, qy[k], fmaf(p1.z, qz[k], p1.w)));
            m0[k] = fminf(m0[k], t0);
            m1[k] = fminf(m1[k], t1);
        }
    }

    float4 o0, o1;
    o0.x = fminf(m0[0], m1[0]); o0.y = fminf(m0[1], m1[1]);
    o0.z = fminf(m0[2], m1[2]); o0.w = fminf(m0[3], m1[3]);
    o1.x = fminf(m0[4], m1[4]); o1.y = fminf(m0[5], m1[5]);
    o1.z = fminf(m0[6], m1[6]); o1.w = fminf(m0[7], m1[7]);

    const size_t qglob = (size_t)dir * (BB * NN) + (size_t)b * NN + qb * QPB + tid * QPT;
    float4* dst = reinterpret_cast<float4*>(minpart + (size_t)c * NQ_TOTAL + qglob);
    dst[0] = o0;
    dst[1] = o1;
}

// combine the NSPLIT partial mins per query, add ||q||^2, block-sum
__global__ __launch_bounds__(THREADS) void decode_sum_kernel(
    const float* __restrict__ a1, const float* __restrict__ a2,
    const float* __restrict__ minpart, float* __restrict__ partials)
{
    __shared__ float red[THREADS];
    const int tid = threadIdx.x;
    const int bid = blockIdx.x;
    const int gq  = bid * THREADS + tid;
    const int dir = gq >> 15;
    const int b   = (gq >> 12) & 7;
    const int q   = gq & (NN - 1);

    float mn = 3.4e38f;
    #pragma unroll
    for (int cc = 0; cc < NSPLIT; ++cc)
        mn = fminf(mn, minpart[(size_t)cc * NQ_TOTAL + gq]);

    const float* qp = (dir == 0 ? a2 : a1) + ((size_t)b * NN + q) * 3;
    const float qx = qp[0], qy = qp[1], qz = qp[2];
    const float qn = fmaf(qx, qx, fmaf(qy, qy, qz * qz));
    const float d  = fmaf(2.0f, mn, qn);   // ||p-q||^2 = 2*t' + ||q||^2

    red[tid] = d;
    __syncthreads();
    #pragma unroll
    for (int s = THREADS / 2; s > 0; s >>= 1) {
        if (tid < s) red[tid] += red[tid + s];
        __syncthreads();
    }
    if (tid == 0) partials[bid] = red[0];
}

__global__ __launch_bounds__(256) void finalize_kernel(
    const float* __restrict__ partials, float* __restrict__ out)
{
    __shared__ float red[256];
    const int t = threadIdx.x;
    red[t] = partials[t];
    __syncthreads();
    #pragma unroll
    for (int s = 64; s > 0; s >>= 1) {
        if ((t & 127) < s) red[t] += red[t + s];
        __syncthreads();
    }
    if (t == 0) {
        const float inv = 1.0f / (float)(BB * NN);
        const float d1 = red[0]   * inv;   // dir0
        const float d2 = red[128] * inv;   // dir1
        out[0] = d1 + d2;
        out[1] = d1;
        out[2] = d2;
    }
}

extern "C" void kernel_launch(void* const* d_in, const int* in_sizes, int n_in,
                              void* d_out, int out_size, void* d_ws, size_t ws_size,
                              hipStream_t stream)
{
    const float* a1 = (const float*)d_in[0];
    const float* a2 = (const float*)d_in[1];
    float* out = (float*)d_out;

    float* minpart = (float*)d_ws;                                   // 16*65536*4 = 4 MB
    float* partials = (float*)((char*)d_ws + (size_t)NSPLIT * NQ_TOTAL * sizeof(float));

    hipLaunchKernelGGL(chamfer_min_kernel, dim3(2 * BB * 2 * NSPLIT), dim3(THREADS), 0, stream,
                       a1, a2, minpart);
    hipLaunchKernelGGL(decode_sum_kernel, dim3(NQ_TOTAL / THREADS), dim3(THREADS), 0, stream,
                       a1, a2, minpart, partials);
    hipLaunchKernelGGL(finalize_kernel, dim3(1), dim3(256), 0, stream,
                       partials, out);
}